// Round 9
// baseline (32.808 us; speedup 1.0000x reference)
//
#include <hip/hip_runtime.h>
#include <hip/hip_bf16.h>
#include <math.h>

typedef __bf16 bf16_t;
typedef __attribute__((ext_vector_type(8))) __bf16 bf16x8;
typedef __attribute__((ext_vector_type(4))) float f32x4;

#define NN 2048
#define CC 256
#define BB 16

// Sub-transforms (out[k], k=0..2047):
//  EE: out[4i]   = sum_{p=0}^{256} ee[p] cos(2pi*p*i/512),       i=0..255 (+mirror; k=1024 via GEMV)
//  EO: out[4i+2] = sum_{m=0}^{255} eo[m] cos(2pi*m*(2i+1)/1024), i=0..255 (+mirror)
//  O : out[2j+1] = sum_{m=0}^{511} o[m]  cos(2pi*m*(2j+1)/2048), j=0..511 (+mirror)
//  O K-axis PERMUTED: u<256 -> m=u ; u==256 -> m=256 ; u>256 -> m=768-u
#define KEE 320            // 257 padded to 5*64
#define KEO 256
#define KO  512

#define ANG2 (6.283185307179586f / 2048.0f)
#define ANG1 (6.283185307179586f / 1024.0f)
#define ANG0 (6.283185307179586f / 512.0f)

union V8 { bf16_t h[8]; uint4 v; };

// chunk-XOR swizzle within aligned groups of 8 16B-chunks
__device__ __forceinline__ int swz8(int p, int colk) {
    const int c = p >> 3;
    return (((c & ~7) | ((c & 7) ^ colk)) << 3) + (p & 7);
}

// ---------------- kernel 1: build A matrices (R6-proven verbatim) ----------
#define NBLK_AEE 40
#define NBLK_AEO 32
#define NBLK_AO  128
#define NBLK_A   (NBLK_AEE + NBLK_AEO + NBLK_AO)

__global__ __launch_bounds__(256) void build_A_kernel(
    bf16_t* __restrict__ Aee, bf16_t* __restrict__ Aeo, bf16_t* __restrict__ Ao)
{
    const int blk = blockIdx.x;
    const int t = threadIdx.x;

    if (blk < NBLK_AEE) {              // Aee[i][p] = cos(2pi*p*i/512), zero p>256
        const int u = blk * 256 + t;
        const int i = u / 40;
        const int p0 = (u - i * 40) * 8;
        const unsigned step = (unsigned)i & 511u;
        unsigned ph = ((unsigned)i * (unsigned)p0) & 511u;
        V8 vals;
#pragma unroll
        for (int q = 0; q < 8; ++q) {
            vals.h[q] = (p0 + q <= 256) ? (bf16_t)cosf((float)ph * ANG0) : (bf16_t)0.0f;
            ph = (ph + step) & 511u;
        }
        *reinterpret_cast<uint4*>(Aee + (size_t)i * KEE + p0) = vals.v;
        return;
    }
    if (blk < NBLK_AEE + NBLK_AEO) {   // Aeo[i][m] = cos(2pi*m*(2i+1)/1024)
        const int u = (blk - NBLK_AEE) * 256 + t;
        const int i = u >> 5;
        const int m0 = (u & 31) * 8;
        const unsigned tw = 2u * (unsigned)i + 1u;
        unsigned ph = ((unsigned)m0 * tw) & 1023u;
        V8 vals;
#pragma unroll
        for (int q = 0; q < 8; ++q) {
            vals.h[q] = (bf16_t)cosf((float)ph * ANG1);
            ph = (ph + tw) & 1023u;
        }
        *reinterpret_cast<uint4*>(Aeo + (size_t)i * KEO + m0) = vals.v;
        return;
    }
    {                                  // Ao[j][u] = cos(2pi*m(u)*(2j+1)/2048)
        const int u = (blk - NBLK_AEE - NBLK_AEO) * 256 + t;
        const int j = u >> 6;
        const int u0 = (u & 63) * 8;
        const unsigned tw = 2u * (unsigned)j + 1u;
        V8 vals;
#pragma unroll
        for (int q = 0; q < 8; ++q) {
            const int uu = u0 + q;
            const int m = (uu <= 256) ? uu : (768 - uu);
            const unsigned ph = ((unsigned)m * tw) & 2047u;
            vals.h[q] = (bf16_t)cosf((float)ph * ANG2);
        }
        *reinterpret_cast<uint4*>(Ao + (size_t)j * KO + u0) = vals.v;
    }
}

// ---------------- section: M=256 x N=32, A direct from global (L2-hot) -----
// No LDS staging for A, no barriers: each wave owns rows w*32..w*32+31 and
// streams A fragments global->reg, B fragments from swizzled Y LDS.
template<int K, int MODE>
__device__ __forceinline__ void section(
    const bf16_t* __restrict__ A, const bf16_t* __restrict__ Ylds,
    float* __restrict__ outb, const int cb, const int t)
{
    constexpr int CHUNKS = K / 32;
    const int lane = t & 63;
    const int w = t >> 6;              // 0..7
    const int lrow = lane & 15;
    const int rgrp = lane >> 4;        // 0..3
    const int lk = lrow & 7;

    const bf16_t* Ar0 = A + (size_t)(w * 32 + lrow) * K + rgrp * 8;
    const bf16_t* Ar1 = Ar0 + (size_t)16 * K;
    const bf16_t* Yl0 = Ylds + (size_t)lrow * K;
    const bf16_t* Yl1 = Ylds + (size_t)(16 + lrow) * K;

    f32x4 acc00 = {0,0,0,0}, acc01 = {0,0,0,0}, acc10 = {0,0,0,0}, acc11 = {0,0,0,0};
#pragma unroll
    for (int ch = 0; ch < CHUNKS; ++ch) {
        const int koff = ch * 32;
        const bf16x8 a0 = *(const bf16x8*)(Ar0 + koff);
        const bf16x8 a1 = *(const bf16x8*)(Ar1 + koff);
        const int g = ch * 4 + rgrp;
        const int phys = (((g & ~7) | ((g & 7) ^ lk)) << 3);
        const bf16x8 b0 = *(const bf16x8*)(Yl0 + phys);
        const bf16x8 b1 = *(const bf16x8*)(Yl1 + phys);
        acc00 = __builtin_amdgcn_mfma_f32_16x16x32_bf16(a0, b0, acc00, 0, 0, 0);
        acc01 = __builtin_amdgcn_mfma_f32_16x16x32_bf16(a0, b1, acc01, 0, 0, 0);
        acc10 = __builtin_amdgcn_mfma_f32_16x16x32_bf16(a1, b0, acc10, 0, 0, 0);
        acc11 = __builtin_amdgcn_mfma_f32_16x16x32_bf16(a1, b1, acc11, 0, 0, 0);
    }
    // epilogue: D col = lane&15, row = rgrp*4 + r
#pragma unroll
    for (int m = 0; m < 2; ++m) {
#pragma unroll
        for (int n = 0; n < 2; ++n) {
            const f32x4 a = m ? (n ? acc11 : acc10) : (n ? acc01 : acc00);
            const int cc = cb + n * 16 + lrow;
#pragma unroll
            for (int r = 0; r < 4; ++r) {
                const int i = w * 32 + m * 16 + rgrp * 4 + r;   // 0..255
                const float v = a[r];
                if (MODE == 0) {
                    outb[(size_t)(4 * i) * CC + cc] = v;
                    if (i >= 1) outb[(size_t)(2048 - 4 * i) * CC + cc] = v;
                } else if (MODE == 1) {
                    outb[(size_t)(4 * i + 2) * CC + cc] = v;
                    outb[(size_t)(2046 - 4 * i) * CC + cc] = v;
                } else if (MODE == 2) {
                    outb[(size_t)(2 * i + 1) * CC + cc] = v;
                    outb[(size_t)(2047 - 2 * i) * CC + cc] = v;
                } else {
                    outb[(size_t)(513 + 2 * i) * CC + cc] = v;
                    outb[(size_t)(1535 - 2 * i) * CC + cc] = v;
                }
            }
        }
    }
}

// ---------------- kernel 2: fused fold + GEMM, 256 blocks x 512 thr --------
// group = bid>>7 (same XCD as its pair bid&127 -> shared-x L2 hits):
//   g0: EE + O-hi + GEMV(k=1024) ; g1: EO + O-lo
#define FK_YO 0                    // Yo: 32 cols x 512
#define FK_YE 16384                // Ye: 32 cols x 320 (g0) / x 256 (g1)

__global__ __launch_bounds__(512) void fused2_kernel(
    const float* __restrict__ x,
    const bf16_t* __restrict__ Aee, const bf16_t* __restrict__ Aeo,
    const bf16_t* __restrict__ Ao, float* __restrict__ out)
{
    __shared__ bf16_t Y[16384 + 10240];   // 53.25 KB
    __shared__ float red[32][17];

    const int bid = blockIdx.x;
    const int group = bid >> 7;
    const int ct = bid & 127;
    const int gc0 = ct * 32;
    const int b = gc0 >> 8;
    const int cb = gc0 & 255;
    const int t = threadIdx.x;
    const int col = t & 31;
    const int pr = t >> 5;            // 0..15
    const int colk = col & 7;

    // zero Ye pad region p=256..319 (g0; ee256 overwrites its slot later)
    if (group == 0 && t < 256) {
        const int zc = t >> 3, zch = 32 + (t & 7);
        *reinterpret_cast<uint4*>(&Y[FK_YE + zc * KEE + zch * 8]) =
            make_uint4(0, 0, 0, 0);
    }
    __syncthreads();

    // ---- fold (R5/R6-proven math), straight into swizzled LDS ----
    const float* xcol = x + (size_t)b * NN * CC + cb + col;
    const int KE = (group == 0) ? KEE : KEO;
    float gacc = 0.f;
#pragma unroll 4
    for (int j = 0; j < 16; ++j) {
        const int p = pr + 16 * j;
        const int n2 = 512 - p, n3 = 512 + p, n4 = 1024 - p;
        const int n5 = 1024 + p, n6 = 1536 - p, n7 = 1536 + p;
        const int n8 = (2048 - p) & 2047;
        const float x1 = xcol[(size_t)p  * CC];
        const float x2 = xcol[(size_t)n2 * CC];
        const float x3 = xcol[(size_t)n3 * CC];
        const float x4 = xcol[(size_t)n4 * CC];
        const float x5 = xcol[(size_t)n5 * CC];
        const float x6 = xcol[(size_t)n6 * CC];
        const float x7 = xcol[(size_t)n7 * CC];
        const float x8 = xcol[(size_t)n8 * CC];
        const float wgt = (p == 0) ? 0.5f : 1.0f;
        const float e_lo = wgt * ((x1 + x4) + (x5 + x8));
        const float e_hi = wgt * ((x2 + x3) + (x6 + x7));
        const float ol = wgt * ((x1 - x5) - (x4 - x8));
        float oh = (x2 - x6) - (x3 - x7);      // o[512-p] -> slot u=256+p
        if (p == 0) {                          // slot u=256 carries o[256]
            const float a  = xcol[(size_t)256  * CC];
            const float bb = xcol[(size_t)768  * CC];
            const float c  = xcol[(size_t)1280 * CC];
            const float d  = xcol[(size_t)1792 * CC];
            oh = (a - c) - (bb - d);
        }
        const float ev = (group == 0) ? (e_lo + e_hi) : (e_lo - e_hi);
        Y[FK_YE + col * KE + swz8(p, colk)] = (bf16_t)ev;
        Y[FK_YO + col * KO + swz8(p, colk)] = (bf16_t)ol;
        Y[FK_YO + col * KO + swz8(256 + p, colk)] = (bf16_t)oh;
        if (group == 0) gacc += (pr & 1) ? -(e_lo + e_hi) : (e_lo + e_hi);
    }
    float ee256 = 0.f;
    if (group == 0) {
        red[col][pr] = gacc;
        if (t < 32) {
            const float* xc2 = x + (size_t)b * NN * CC + cb + t;
            ee256 = (xc2[(size_t)256 * CC] + xc2[(size_t)768 * CC]) +
                    (xc2[(size_t)1280 * CC] + xc2[(size_t)1792 * CC]);
            Y[FK_YE + t * KEE + swz8(256, t & 7)] = (bf16_t)ee256;
        }
    }
    __syncthreads();

    float* outb = out + (size_t)b * NN * CC;
    if (group == 0) {
        if (t < 32) {                  // GEMV: out[1024][c] = sum (-1)^p ee[p]
            float s = ee256;
#pragma unroll
            for (int q = 0; q < 16; ++q) s += red[t][q];
            outb[(size_t)1024 * CC + cb + t] = s;
        }
        section<KEE, 0>(Aee, &Y[FK_YE], outb, cb, t);
        section<KO,  3>(Ao + (size_t)256 * KO, &Y[FK_YO], outb, cb, t);
    } else {
        section<KEO, 1>(Aeo, &Y[FK_YE], outb, cb, t);
        section<KO,  2>(Ao, &Y[FK_YO], outb, cb, t);
    }
}

// ---------------- fallback (no/small ws): correct but slow ----------------

__global__ void fallback_kernel(const float* __restrict__ x, float* __restrict__ out) {
    __shared__ float tbl[NN];
    const int b = blockIdx.y;
    const int kbase = blockIdx.x * 16;
    const int t = threadIdx.x;  // 256 = C
    for (int i = t; i < NN; i += 256)
        tbl[i] = cosf((float)i * ANG2);
    __syncthreads();
    float acc[16];
#pragma unroll
    for (int kk = 0; kk < 16; ++kk) acc[kk] = 0.f;
    const float* xb = x + (size_t)b * NN * CC;
    for (int n = 0; n < NN; ++n) {
        const float xv = xb[(size_t)n * CC + t];
#pragma unroll
        for (int kk = 0; kk < 16; ++kk) {
            const int m = (n * (kbase + kk)) & (NN - 1);
            acc[kk] += tbl[m] * xv;
        }
    }
#pragma unroll
    for (int kk = 0; kk < 16; ++kk)
        out[((size_t)b * NN + kbase + kk) * CC + t] = acc[kk];
}

extern "C" void kernel_launch(void* const* d_in, const int* in_sizes, int n_in,
                              void* d_out, int out_size, void* d_ws, size_t ws_size,
                              hipStream_t stream) {
    const float* x = (const float*)d_in[0];
    float* out = (float*)d_out;

    const size_t Aee_b = (size_t)256 * KEE * 2;      // 163,840
    const size_t Aeo_b = (size_t)256 * KEO * 2;      // 131,072
    const size_t Ao_b  = (size_t)512 * KO  * 2;      // 524,288
    const size_t need = Aee_b + Aeo_b + Ao_b;        // ~0.8 MB

    if (ws_size >= need) {
        char* p = (char*)d_ws;
        bf16_t* Aee = (bf16_t*)p;              p += Aee_b;
        bf16_t* Aeo = (bf16_t*)p;              p += Aeo_b;
        bf16_t* Ao  = (bf16_t*)p;
        build_A_kernel<<<NBLK_A, 256, 0, stream>>>(Aee, Aeo, Ao);
        fused2_kernel<<<256, 512, 0, stream>>>(x, Aee, Aeo, Ao, out);
    } else {
        fallback_kernel<<<dim3(NN / 16, BB), CC, 0, stream>>>(x, out);
    }
}

// Round 10
// 27.592 us; speedup vs baseline: 1.1890x; 1.1890x over previous
//
#include <hip/hip_runtime.h>
#include <hip/hip_bf16.h>
#include <math.h>

typedef __bf16 bf16_t;
typedef __attribute__((ext_vector_type(8))) __bf16 bf16x8;
typedef __attribute__((ext_vector_type(4))) float f32x4;

#define NN 2048
#define CC 256
#define BB 16
#define COLS 4096          // flattened (b,c)

// Sub-transforms (out[k], k=0..2047):
//  EE: out[4i]   = sum_{p=0}^{256} ee[p] cos(2pi*p*i/512),       i=0..255 (+mirror; k=1024 via GEMV)
//  EO: out[4i+2] = sum_{m=0}^{255} eo[m] cos(2pi*m*(2i+1)/1024), i=0..255 (+mirror)
//  O : out[2j+1] = sum_{m=0}^{511} o[m]  cos(2pi*m*(2j+1)/2048), j=0..511 (+mirror)
//  O K-axis PERMUTED: u<256 -> m=u ; u==256 -> m=256 ; u>256 -> m=768-u
#define KEE 320            // 257 padded to 5*64
#define MEE 256
#define KEO 256
#define KO  512

#define ANG2 (6.283185307179586f / 2048.0f)
#define ANG1 (6.283185307179586f / 1024.0f)
#define ANG0 (6.283185307179586f / 512.0f)

__device__ __forceinline__ void gload_lds16(const void* g, void* l) {
    __builtin_amdgcn_global_load_lds(
        (const __attribute__((address_space(1))) void*)g,
        (__attribute__((address_space(3))) void*)l, 16, 0, 0);
}

union V8 { bf16_t h[8]; uint4 v; };
union V4 { bf16_t h[4]; uint2 v; };
union F4 { float4 v; float f[4]; };

// ---------------- prologue: A-build + vectorized fold ----------------------
// blocks: [0,200) A-build | [200,712) fold (float4 reads + LDS transpose)
#define NBLK_AEE 40
#define NBLK_AEO 32
#define NBLK_AO  128
#define NBLK_A   (NBLK_AEE + NBLK_AEO + NBLK_AO)
#define NBLK_FOLD 512
#define PREP_BLOCKS (NBLK_A + NBLK_FOLD)

__global__ __launch_bounds__(256) void prep_kernel(
    const float* __restrict__ x,
    bf16_t* __restrict__ Aee, bf16_t* __restrict__ Aeo, bf16_t* __restrict__ Ao,
    bf16_t* __restrict__ Yee, bf16_t* __restrict__ Yeo, bf16_t* __restrict__ Yo)
{
    __shared__ bf16_t Tee[32][72], Teo[32][72], Tol[32][72], Toh[32][72];
    const int blk = blockIdx.x;
    const int t = threadIdx.x;

    if (blk < NBLK_AEE) {              // Aee[i][p] = cos(2pi*p*i/512), zero p>256
        const int u = blk * 256 + t;
        const int i = u / 40;
        const int p0 = (u - i * 40) * 8;
        const unsigned step = (unsigned)i & 511u;
        unsigned ph = ((unsigned)i * (unsigned)p0) & 511u;
        V8 vals;
#pragma unroll
        for (int q = 0; q < 8; ++q) {
            vals.h[q] = (p0 + q <= 256) ? (bf16_t)cosf((float)ph * ANG0) : (bf16_t)0.0f;
            ph = (ph + step) & 511u;
        }
        *reinterpret_cast<uint4*>(Aee + (size_t)i * KEE + p0) = vals.v;
        return;
    }
    if (blk < NBLK_AEE + NBLK_AEO) {   // Aeo[i][m] = cos(2pi*m*(2i+1)/1024)
        const int u = (blk - NBLK_AEE) * 256 + t;
        const int i = u >> 5;
        const int m0 = (u & 31) * 8;
        const unsigned tw = 2u * (unsigned)i + 1u;
        unsigned ph = ((unsigned)m0 * tw) & 1023u;
        V8 vals;
#pragma unroll
        for (int q = 0; q < 8; ++q) {
            vals.h[q] = (bf16_t)cosf((float)ph * ANG1);
            ph = (ph + tw) & 1023u;
        }
        *reinterpret_cast<uint4*>(Aeo + (size_t)i * KEO + m0) = vals.v;
        return;
    }
    if (blk < NBLK_A) {                // Ao[j][u] = cos(2pi*m(u)*(2j+1)/2048)
        const int u = (blk - NBLK_AEE - NBLK_AEO) * 256 + t;
        const int j = u >> 6;
        const int u0 = (u & 63) * 8;
        const unsigned tw = 2u * (unsigned)j + 1u;
        V8 vals;
#pragma unroll
        for (int q = 0; q < 8; ++q) {
            const int uu = u0 + q;
            const int m = (uu <= 256) ? uu : (768 - uu);
            const unsigned ph = ((unsigned)m * tw) & 2047u;
            vals.h[q] = (bf16_t)cosf((float)ph * ANG2);
        }
        *reinterpret_cast<uint4*>(Ao + (size_t)j * KO + u0) = vals.v;
        return;
    }

    // ---- fold: (p-tile, col-tile); float4 reads, LDS transpose, 16B writes ----
    const int f = blk - NBLK_A;
    const int pt = f >> 6;             // 0..7
    const int ct = f & 63;             // 0..63
    const int gc0 = ct * 64;
    const int b = gc0 >> 8;
    const int cb = gc0 & 255;
    const int c4 = (t & 15) * 4;       // 4-col group
    const int pidx = t >> 4;           // 0..15

    const float* xb = x + (size_t)b * NN * CC + cb + c4;

#pragma unroll
    for (int pp = 0; pp < 2; ++pp) {
        const int prow = pidx + pp * 16;
        const int p = pt * 32 + prow;
        const int n2 = 512 - p, n3 = 512 + p, n4 = 1024 - p;
        const int n5 = 1024 + p, n6 = 1536 - p, n7 = 1536 + p;
        const int n8 = (2048 - p) & 2047;
        F4 x1, x2, x3, x4, x5, x6, x7, x8;
        x1.v = *reinterpret_cast<const float4*>(xb + (size_t)p  * CC);
        x2.v = *reinterpret_cast<const float4*>(xb + (size_t)n2 * CC);
        x3.v = *reinterpret_cast<const float4*>(xb + (size_t)n3 * CC);
        x4.v = *reinterpret_cast<const float4*>(xb + (size_t)n4 * CC);
        x5.v = *reinterpret_cast<const float4*>(xb + (size_t)n5 * CC);
        x6.v = *reinterpret_cast<const float4*>(xb + (size_t)n6 * CC);
        x7.v = *reinterpret_cast<const float4*>(xb + (size_t)n7 * CC);
        x8.v = *reinterpret_cast<const float4*>(xb + (size_t)n8 * CC);
        F4 a4, b4, cc4, d4;
        if (p == 0) {                  // slot u=256 carries o[256]
            a4.v  = *reinterpret_cast<const float4*>(xb + (size_t)256  * CC);
            b4.v  = *reinterpret_cast<const float4*>(xb + (size_t)768  * CC);
            cc4.v = *reinterpret_cast<const float4*>(xb + (size_t)1280 * CC);
            d4.v  = *reinterpret_cast<const float4*>(xb + (size_t)1792 * CC);
        }
        const float wgt = (p == 0) ? 0.5f : 1.0f;
        V4 vee, veo, vol, voh;
#pragma unroll
        for (int q = 0; q < 4; ++q) {
            const float e_lo = wgt * ((x1.f[q] + x4.f[q]) + (x5.f[q] + x8.f[q]));
            const float e_hi = wgt * ((x2.f[q] + x3.f[q]) + (x6.f[q] + x7.f[q]));
            const float ol = wgt * ((x1.f[q] - x5.f[q]) - (x4.f[q] - x8.f[q]));
            float oh = (x2.f[q] - x6.f[q]) - (x3.f[q] - x7.f[q]);
            if (p == 0) oh = (a4.f[q] - cc4.f[q]) - (b4.f[q] - d4.f[q]);
            vee.h[q] = (bf16_t)(e_lo + e_hi);
            veo.h[q] = (bf16_t)(e_lo - e_hi);
            vol.h[q] = (bf16_t)ol;
            voh.h[q] = (bf16_t)oh;
        }
        *reinterpret_cast<uint2*>(&Tee[prow][c4]) = vee.v;
        *reinterpret_cast<uint2*>(&Teo[prow][c4]) = veo.v;
        *reinterpret_cast<uint2*>(&Tol[prow][c4]) = vol.v;
        *reinterpret_cast<uint2*>(&Toh[prow][c4]) = voh.v;
    }
    __syncthreads();

    // write-out: thread (col, chunk) gathers 8 p from LDS -> one 16B store each
    {
        const int col = t & 63;
        const int chunk = t >> 6;      // 0..3
        const size_t gcol = (size_t)(gc0 + col);
        const int kbase = pt * 32 + chunk * 8;
        V8 vee, veo, vol, voh;
#pragma unroll
        for (int i = 0; i < 8; ++i) {
            const int r = chunk * 8 + i;
            vee.h[i] = Tee[r][col];
            veo.h[i] = Teo[r][col];
            vol.h[i] = Tol[r][col];
            voh.h[i] = Toh[r][col];
        }
        *reinterpret_cast<uint4*>(Yee + gcol * KEE + kbase) = vee.v;
        *reinterpret_cast<uint4*>(Yeo + gcol * KEO + kbase) = veo.v;
        *reinterpret_cast<uint4*>(Yo  + gcol * KO  + kbase) = vol.v;
        *reinterpret_cast<uint4*>(Yo  + gcol * KO  + 256 + kbase) = voh.v;
    }

    // pt==0 blocks also handle ee[256] + Yee pad 257..319 (was separate blocks)
    if (pt == 0 && t < 64) {
        const float* xc2 = x + (size_t)b * NN * CC + cb + t;
        const float ee256 = (xc2[(size_t)256 * CC] + xc2[(size_t)768 * CC]) +
                            (xc2[(size_t)1280 * CC] + xc2[(size_t)1792 * CC]);
        bf16_t* base = Yee + (size_t)(gc0 + t) * KEE + 256;
        V8 z; z.v = make_uint4(0, 0, 0, 0);
        V8 first = z; first.h[0] = (bf16_t)ee256;
        *reinterpret_cast<uint4*>(base) = first.v;
#pragma unroll
        for (int ch = 1; ch < 8; ++ch)
            *reinterpret_cast<uint4*>(base + ch * 8) = z.v;
    }
}

// ---------------- triple GEMM + GEMV, one launch (26.83µs-proven, VERBATIM) --
// grid (64, 13): y 0..3 EE (BM=64), 4..7 EO (BM=64), 8..11 O (BM=128), 12 GEMV.
// Double-buffered LDS prefetch + XOR chunk-swizzle (linear gload_lds dest,
// pre-swizzled global source, swizzled ds_read).

__global__ __launch_bounds__(256) void gemm_kernel(
    const bf16_t* __restrict__ Aee, const bf16_t* __restrict__ Aeo,
    const bf16_t* __restrict__ Ao,
    const bf16_t* __restrict__ Yee, const bf16_t* __restrict__ Yeo,
    const bf16_t* __restrict__ Yo, float* __restrict__ out)
{
    __shared__ bf16_t As[2][128 * 64];   // 32 KB
    __shared__ bf16_t Bs[2][64 * 64];    // 16 KB
    __shared__ float red[64][4];

    const int col0 = blockIdx.x * 64;
    const int yb = blockIdx.y;
    const int t = threadIdx.x;

    if (yb == 12) {                    // ---- GEMV: out[1024][c] = sum (-1)^p ee[p]
        const int col = t & 63;
        const int part = t >> 6;
        const bf16_t* yc = Yee + (size_t)(col0 + col) * KEE + part * 80;
        float s = 0.f;
#pragma unroll
        for (int jc = 0; jc < 10; ++jc) {
            const bf16x8 v = *reinterpret_cast<const bf16x8*>(yc + jc * 8);
#pragma unroll
            for (int q = 0; q < 8; ++q)
                s += (q & 1) ? -(float)v[q] : (float)v[q];
        }
        red[col][part] = s;
        __syncthreads();
        if (t < 64) {
            const float tot = (red[t][0] + red[t][1]) + (red[t][2] + red[t][3]);
            const int gc = col0 + t;
            out[(size_t)(gc >> 8) * NN * CC + (size_t)1024 * CC + (gc & 255)] = tot;
        }
        return;
    }

    const bf16_t *Ab, *Bb;
    int row0, kdim, half;
    if (yb < 4)      { half = 0; row0 = yb * 64;        kdim = KEE; Ab = Aee + (size_t)row0 * KEE; Bb = Yee + (size_t)col0 * KEE; }
    else if (yb < 8) { half = 1; row0 = (yb - 4) * 64;  kdim = KEO; Ab = Aeo + (size_t)row0 * KEO; Bb = Yeo + (size_t)col0 * KEO; }
    else             { half = 2; row0 = (yb - 8) * 128; kdim = KO;  Ab = Ao  + (size_t)row0 * KO;  Bb = Yo  + (size_t)col0 * KO; }
    const int ksteps = kdim >> 6;

    const int lane = t & 63;
    const int wid = t >> 6;
    const int wr = wid >> 1, wc = wid & 1;
    const int srow = t >> 3;             // 0..31
    const int sc_chunk = t & 7;          // 16B-chunk index within the 64-elem row
    const int s_swz = (sc_chunk ^ (srow & 7)) * 8;   // swizzled source elem offset
    const int lds_lin = srow * 64 + sc_chunk * 8;    // linear dest elem offset
    const int lrow = lane & 15;
    const int rx8 = lrow & 7;            // read-side swizzle key
    const int rgrp = lane >> 4;
    const int cl = lane & 15;
    const int hi8 = (lane >> 4) * 8;     // koff base within kk-group

    if (half == 2) {                   // ---- O: BM=128, ksteps=8 ----
        f32x4 acc[4][2] = {};
        int cur = 0;
#pragma unroll
        for (int it = 0; it < 4; ++it)
            gload_lds16(Ab + (size_t)(srow + it * 32) * KO + s_swz,
                        &As[0][lds_lin + it * 2048]);
#pragma unroll
        for (int it = 0; it < 2; ++it)
            gload_lds16(Bb + (size_t)(srow + it * 32) * KO + s_swz,
                        &Bs[0][lds_lin + it * 2048]);
        __syncthreads();
        for (int kt = 0; kt < 8; ++kt) {
            if (kt + 1 < 8) {
                const int k0 = (kt + 1) * 64;
#pragma unroll
                for (int it = 0; it < 4; ++it)
                    gload_lds16(Ab + (size_t)(srow + it * 32) * KO + k0 + s_swz,
                                &As[cur ^ 1][lds_lin + it * 2048]);
#pragma unroll
                for (int it = 0; it < 2; ++it)
                    gload_lds16(Bb + (size_t)(srow + it * 32) * KO + k0 + s_swz,
                                &Bs[cur ^ 1][lds_lin + it * 2048]);
            }
            const bf16_t* as = &As[cur][0];
            const bf16_t* bs = &Bs[cur][0];
#pragma unroll
            for (int kk = 0; kk < 64; kk += 32) {
                const int g = (kk + hi8) >> 3;           // global chunk 0..7
                const int rc = ((g ^ rx8) * 8);          // swizzled read offset
                bf16x8 af[4], bfr[2];
#pragma unroll
                for (int m = 0; m < 4; ++m)
                    af[m] = *(const bf16x8*)&as[(wr * 64 + m * 16 + lrow) * 64 + rc];
#pragma unroll
                for (int n = 0; n < 2; ++n)
                    bfr[n] = *(const bf16x8*)&bs[(wc * 32 + n * 16 + lrow) * 64 + rc];
#pragma unroll
                for (int m = 0; m < 4; ++m)
#pragma unroll
                    for (int n = 0; n < 2; ++n)
                        acc[m][n] = __builtin_amdgcn_mfma_f32_16x16x32_bf16(
                            af[m], bfr[n], acc[m][n], 0, 0, 0);
            }
            __syncthreads();
            cur ^= 1;
        }
#pragma unroll
        for (int m = 0; m < 4; ++m)
#pragma unroll
            for (int n = 0; n < 2; ++n) {
                const int col = col0 + wc * 32 + n * 16 + cl;
                float* obc = out + (size_t)(col >> 8) * NN * CC + (col & 255);
#pragma unroll
                for (int r = 0; r < 4; ++r) {
                    const int j = row0 + wr * 64 + m * 16 + rgrp * 4 + r;
                    const float v = acc[m][n][r];
                    obc[(size_t)(2 * j + 1) * CC] = v;
                    obc[(size_t)(2047 - 2 * j) * CC] = v;
                }
            }
    } else {                           // ---- EE / EO: BM=64 ----
        f32x4 acc[2][2] = {};
        int cur = 0;
#pragma unroll
        for (int it = 0; it < 2; ++it) {
            const size_t ro = (size_t)(srow + it * 32) * kdim + s_swz;
            gload_lds16(Ab + ro, &As[0][lds_lin + it * 2048]);
            gload_lds16(Bb + ro, &Bs[0][lds_lin + it * 2048]);
        }
        __syncthreads();
        for (int kt = 0; kt < ksteps; ++kt) {
            if (kt + 1 < ksteps) {
                const int k0 = (kt + 1) * 64;
#pragma unroll
                for (int it = 0; it < 2; ++it) {
                    const size_t ro = (size_t)(srow + it * 32) * kdim + k0 + s_swz;
                    gload_lds16(Ab + ro, &As[cur ^ 1][lds_lin + it * 2048]);
                    gload_lds16(Bb + ro, &Bs[cur ^ 1][lds_lin + it * 2048]);
                }
            }
            const bf16_t* as = &As[cur][0];
            const bf16_t* bs = &Bs[cur][0];
#pragma unroll
            for (int kk = 0; kk < 64; kk += 32) {
                const int g = (kk + hi8) >> 3;
                const int rc = ((g ^ rx8) * 8);
                bf16x8 af[2], bfr[2];
#pragma unroll
                for (int m = 0; m < 2; ++m)
                    af[m] = *(const bf16x8*)&as[(wr * 32 + m * 16 + lrow) * 64 + rc];
#pragma unroll
                for (int n = 0; n < 2; ++n)
                    bfr[n] = *(const bf16x8*)&bs[(wc * 32 + n * 16 + lrow) * 64 + rc];
#pragma unroll
                for (int m = 0; m < 2; ++m)
#pragma unroll
                    for (int n = 0; n < 2; ++n)
                        acc[m][n] = __builtin_amdgcn_mfma_f32_16x16x32_bf16(
                            af[m], bfr[n], acc[m][n], 0, 0, 0);
            }
            __syncthreads();
            cur ^= 1;
        }
#pragma unroll
        for (int m = 0; m < 2; ++m)
#pragma unroll
            for (int n = 0; n < 2; ++n) {
                const int col = col0 + wc * 32 + n * 16 + cl;
                float* obc = out + (size_t)(col >> 8) * NN * CC + (col & 255);
#pragma unroll
                for (int r = 0; r < 4; ++r) {
                    const int i = row0 + wr * 32 + m * 16 + rgrp * 4 + r;  // 0..255
                    const float v = acc[m][n][r];
                    if (half == 0) {
                        obc[(size_t)(4 * i) * CC] = v;
                        if (i >= 1) obc[(size_t)(2048 - 4 * i) * CC] = v;
                    } else {
                        obc[(size_t)(4 * i + 2) * CC] = v;
                        obc[(size_t)(2046 - 4 * i) * CC] = v;
                    }
                }
            }
    }
}

// ---------------- fallback (no/small ws): correct but slow ----------------

__global__ void fallback_kernel(const float* __restrict__ x, float* __restrict__ out) {
    __shared__ float tbl[NN];
    const int b = blockIdx.y;
    const int kbase = blockIdx.x * 16;
    const int t = threadIdx.x;  // 256 = C
    for (int i = t; i < NN; i += 256)
        tbl[i] = cosf((float)i * ANG2);
    __syncthreads();
    float acc[16];
#pragma unroll
    for (int kk = 0; kk < 16; ++kk) acc[kk] = 0.f;
    const float* xb = x + (size_t)b * NN * CC;
    for (int n = 0; n < NN; ++n) {
        const float xv = xb[(size_t)n * CC + t];
#pragma unroll
        for (int kk = 0; kk < 16; ++kk) {
            const int m = (n * (kbase + kk)) & (NN - 1);
            acc[kk] += tbl[m] * xv;
        }
    }
#pragma unroll
    for (int kk = 0; kk < 16; ++kk)
        out[((size_t)b * NN + kbase + kk) * CC + t] = acc[kk];
}

extern "C" void kernel_launch(void* const* d_in, const int* in_sizes, int n_in,
                              void* d_out, int out_size, void* d_ws, size_t ws_size,
                              hipStream_t stream) {
    const float* x = (const float*)d_in[0];
    float* out = (float*)d_out;

    const size_t Aee_b = (size_t)MEE * KEE * 2;      // 163,840
    const size_t Aeo_b = (size_t)256 * KEO * 2;      // 131,072
    const size_t Ao_b  = (size_t)512 * KO  * 2;      // 524,288
    const size_t Yee_b = (size_t)COLS * KEE * 2;     // 2,621,440
    const size_t Yeo_b = (size_t)COLS * KEO * 2;     // 2,097,152
    const size_t Yo_b  = (size_t)COLS * KO  * 2;     // 4,194,304
    const size_t need = Aee_b + Aeo_b + Ao_b + Yee_b + Yeo_b + Yo_b;

    if (ws_size >= need) {
        char* p = (char*)d_ws;
        bf16_t* Aee = (bf16_t*)p;              p += Aee_b;
        bf16_t* Aeo = (bf16_t*)p;              p += Aeo_b;
        bf16_t* Ao  = (bf16_t*)p;              p += Ao_b;
        bf16_t* Yee = (bf16_t*)p;              p += Yee_b;
        bf16_t* Yeo = (bf16_t*)p;              p += Yeo_b;
        bf16_t* Yo  = (bf16_t*)p;
        prep_kernel<<<PREP_BLOCKS, 256, 0, stream>>>(x, Aee, Aeo, Ao, Yee, Yeo, Yo);
        gemm_kernel<<<dim3(COLS / 64, 13), 256, 0, stream>>>(Aee, Aeo, Ao, Yee, Yeo, Yo, out);
    } else {
        fallback_kernel<<<dim3(NN / 16, BB), CC, 0, stream>>>(x, out);
    }
}